// Round 11
// baseline (155.419 us; speedup 1.0000x reference)
//
#include <hip/hip_runtime.h>
#include <hip/hip_bf16.h>

#define D_MODEL 1024
#define D_STATE 16
#define DT_RANK 64
#define SEQ 2048
#define BATCH 2
#define M_TOTAL 4096
#define CHUNKS 64
#define CLEN 32
#define LOG2E 1.44269504088896f

typedef __bf16 bf16x8 __attribute__((ext_vector_type(8)));
typedef float f32x4 __attribute__((ext_vector_type(4)));

__device__ __forceinline__ unsigned short f2bf(float f) {
    union { float f; unsigned int u; } v; v.f = f;
    unsigned int r = v.u + 0x7FFFu + ((v.u >> 16) & 1u);
    return (unsigned short)(r >> 16);
}
__device__ __forceinline__ float bf2f(unsigned short u) {
    union { unsigned int i; float f; } v; v.i = ((unsigned int)u) << 16; return v.f;
}
__device__ __forceinline__ void gload16(const void* g, void* l) {
    __builtin_amdgcn_global_load_lds(
        (const __attribute__((address_space(1))) unsigned int*)g,
        (__attribute__((address_space(3))) unsigned int*)l, 16, 0, 0);
}
__device__ __forceinline__ float fexp2(float x) { return __builtin_amdgcn_exp2f(x); }

// ---------- fused setup (x-conversion moved into k_gemm_xin; 1728 blocks) ----------
__global__ void __launch_bounds__(256) k_setup(const float* __restrict__ win,
                                               const float* __restrict__ wx,
                                               const float* __restrict__ wdt,
                                               const float* __restrict__ alog,
                                               unsigned short* __restrict__ bt,
                                               unsigned short* __restrict__ wxT,
                                               unsigned short* __restrict__ wxBC,
                                               unsigned short* __restrict__ wdtT,
                                               float* __restrict__ aneg,
                                               unsigned short* __restrict__ anegT) {
    __shared__ float tile[32][33];
    int blk = blockIdx.x;
    int t = threadIdx.x;
    if (blk < 1024) {  // w_in^T -> bt
        int bx = blk & 31, by = blk >> 5;
        int tx = t & 31, ty = t >> 5;
        int xc = bx * 32 + tx;
#pragma unroll
        for (int j = 0; j < 4; j++)
            tile[ty + 8 * j][tx] = win[(by * 32 + ty + 8 * j) * D_MODEL + xc];
        __syncthreads();
        int x2 = by * 32 + tx;
#pragma unroll
        for (int j = 0; j < 4; j++)
            bt[(bx * 32 + ty + 8 * j) * D_MODEL + x2] = f2bf(tile[tx][ty + 8 * j]);
    } else if (blk < 1280) {  // wxT[p][e] = w_x[e][p], p<64
        int idx = (blk - 1024) * 256 + t;
        int e = idx & 1023, p = idx >> 10;
        wxT[p * D_MODEL + e] = f2bf(wx[e * 96 + p]);
    } else if (blk < 1408) {  // wxBC[p][e] = w_x[e][64+p], p<32
        int idx = (blk - 1280) * 256 + t;
        int e = idx & 1023, p = idx >> 10;
        wxBC[p * D_MODEL + e] = f2bf(wx[e * 96 + 64 + p]);
    } else if (blk < 1472) {  // aneg (fp32, [d][n], pre-scaled by log2e) + anegT (bf16, [n][d], UNscaled)
        int i = (blk - 1408) * 256 + t;  // 64 blocks -> 16384 exact
        float v = -expf(alog[i]);
        aneg[i] = v * LOG2E;
        anegT[(i & 15) * D_MODEL + (i >> 4)] = f2bf(v);
    } else {  // wdtT[d][k] = w_dt[k][d] bf16  (256 blocks -> 65536)
        int idx = (blk - 1472) * 256 + t;
        int d = idx & 1023, k = idx >> 10;
        wdtT[d * DT_RANK + k] = f2bf(wdt[k * D_MODEL + d]);
    }
}

// ---------- x_in GEMM: x_in = x @ w_in. A reg-staged from f32 x (cvt inline, same LDS bytes);
// ---------- B via gload16. 64x128 tile, BK=64, dbuf, XOR-swizzle, XCD remap, grid 512. ----------
__global__ void __launch_bounds__(256) k_gemm_xin(const float* __restrict__ x,
                                                  const unsigned short* __restrict__ bt,
                                                  unsigned short* __restrict__ xinb) {
    __shared__ unsigned short sA[2][64 * 64];
    __shared__ unsigned short sB[2][128 * 64];
    int bid0 = blockIdx.x;               // 512, XCD = bid0 % 8
    int bid = (bid0 & 7) * 64 + (bid0 >> 3);
    int m0 = (bid >> 3) * 64;            // m-major within XCD chunk
    int n0 = (bid & 7) * 128;
    int t = threadIdx.x;
    int lane = t & 63;
    int w = t >> 6;
    int wm = (w >> 1) * 32, wn = (w & 1) * 64;
    int c = lane & 15, q = lane >> 4;

    // A source (f32): thread t owns staging slots s = t and s = 256+t
    int s0 = t, s1 = 256 + t;
    int rowA0 = s0 >> 3, chA0 = (s0 & 7) ^ (rowA0 & 7);
    int rowA1 = s1 >> 3, chA1 = (s1 & 7) ^ (rowA1 & 7);
    const float* gxA0 = x + (m0 + rowA0) * D_MODEL + chA0 * 8;
    const float* gxA1 = x + (m0 + rowA1) * D_MODEL + chA1 * 8;

    const unsigned short* gB[4];
#pragma unroll
    for (int L = 0; L < 4; L++) {
        int s = L * 256 + t;
        int row = s >> 3, ch = (s & 7) ^ (row & 7);
        gB[L] = bt + (n0 + row) * D_MODEL + ch * 8;
    }

    auto stageA = [&](int buf, int kn) {
        float4 v0 = *reinterpret_cast<const float4*>(gxA0 + kn);
        float4 v1 = *reinterpret_cast<const float4*>(gxA0 + kn + 4);
        float4 v2 = *reinterpret_cast<const float4*>(gxA1 + kn);
        float4 v3 = *reinterpret_cast<const float4*>(gxA1 + kn + 4);
        ushort4 o0, o1, o2, o3;
        o0.x = f2bf(v0.x); o0.y = f2bf(v0.y); o0.z = f2bf(v0.z); o0.w = f2bf(v0.w);
        o1.x = f2bf(v1.x); o1.y = f2bf(v1.y); o1.z = f2bf(v1.z); o1.w = f2bf(v1.w);
        o2.x = f2bf(v2.x); o2.y = f2bf(v2.y); o2.z = f2bf(v2.z); o2.w = f2bf(v2.w);
        o3.x = f2bf(v3.x); o3.y = f2bf(v3.y); o3.z = f2bf(v3.z); o3.w = f2bf(v3.w);
        *reinterpret_cast<ushort4*>(&sA[buf][s0 * 8]) = o0;
        *reinterpret_cast<ushort4*>(&sA[buf][s0 * 8 + 4]) = o1;
        *reinterpret_cast<ushort4*>(&sA[buf][s1 * 8]) = o2;
        *reinterpret_cast<ushort4*>(&sA[buf][s1 * 8 + 4]) = o3;
    };

    f32x4 acc[2][4] = {};
    {
        stageA(0, 0);
        char* lb = (char*)&sB[0][0] + w * 1024;
#pragma unroll
        for (int L = 0; L < 4; L++) gload16(gB[L], lb + L * 4096);
    }
    int cur = 0;
    for (int it = 0; it < 16; it++) {
        __syncthreads();
        if (it + 1 < 16) {
            int kn = (it + 1) * 64;
            stageA(cur ^ 1, kn);
            char* lb = (char*)&sB[cur ^ 1][0] + w * 1024;
#pragma unroll
            for (int L = 0; L < 4; L++) gload16(gB[L] + kn, lb + L * 4096);
        }
#pragma unroll
        for (int kk = 0; kk < 2; kk++) {
            int perm = (((kk << 2) | q) ^ (c & 7)) << 3;
            bf16x8 af[2], bfr[4];
#pragma unroll
            for (int i = 0; i < 2; i++)
                af[i] = *reinterpret_cast<const bf16x8*>(&sA[cur][(wm + i * 16 + c) * 64 + perm]);
#pragma unroll
            for (int j = 0; j < 4; j++)
                bfr[j] = *reinterpret_cast<const bf16x8*>(&sB[cur][(wn + j * 16 + c) * 64 + perm]);
            // swapped operands: lane owns 4 consecutive n-cols
#pragma unroll
            for (int i = 0; i < 2; i++)
#pragma unroll
                for (int j = 0; j < 4; j++)
                    acc[i][j] = __builtin_amdgcn_mfma_f32_16x16x32_bf16(bfr[j], af[i], acc[i][j], 0, 0, 0);
        }
        cur ^= 1;
    }
#pragma unroll
    for (int i = 0; i < 2; i++) {
        int row = m0 + wm + i * 16 + c;
#pragma unroll
        for (int j = 0; j < 4; j++) {
            int col = n0 + wn + j * 16 + q * 4;
            ushort4 o;
            o.x = f2bf(acc[i][j][0]); o.y = f2bf(acc[i][j][1]);
            o.z = f2bf(acc[i][j][2]); o.w = f2bf(acc[i][j][3]);
            *reinterpret_cast<ushort4*>(&xinb[row * D_MODEL + col]) = o;
        }
    }
}

// ---------- fused dt+BCW: per-block 16 rows.
// phase 1-3 = proven k_dt2 (xlow wave-ksplit -> LDS reduce -> dt GEMM -> dtb).
// phase 4-5 = bcw for the SAME 16 rows (wave-ksplit K=256, LDS reduce) -> FINAL winp/bcC.
__global__ void __launch_bounds__(256) k_dtbcw(const unsigned short* __restrict__ xinb,
                                               const unsigned short* __restrict__ wxT,
                                               const unsigned short* __restrict__ wdtT,
                                               const float* __restrict__ bdt,
                                               const unsigned short* __restrict__ wxBC,
                                               const unsigned short* __restrict__ anegT,
                                               unsigned short* __restrict__ dtb,
                                               float* __restrict__ winp,
                                               float* __restrict__ bcC) {
    __shared__ float sP[4][64][17];        // xlow wave partials, +1 pad
    __shared__ unsigned short sX[16 * 64]; // bf16 xlow tile, XOR-swizzled
    __shared__ float sBC[4][16][49];       // bcw wave partials: [w][row][p<32 | 32+n], +1 pad
    int m0 = blockIdx.x * 16;              // 256 blocks x 16 rows
    int t = threadIdx.x;
    int lane = t & 63, w = t >> 6;
    int c = lane & 15, q = lane >> 4;

    // phase 1: partial xlow over K slice [w*256, +256)
    {
        f32x4 acc[4] = {};
        const unsigned short* pa = xinb + (m0 + c) * D_MODEL + w * 256 + q * 8;
        const unsigned short* pw = wxT + c * D_MODEL + w * 256 + q * 8;
#pragma unroll
        for (int k0 = 0; k0 < 256; k0 += 32) {
            bf16x8 a0 = *reinterpret_cast<const bf16x8*>(pa + k0);
#pragma unroll
            for (int j = 0; j < 4; j++) {
                bf16x8 wf = *reinterpret_cast<const bf16x8*>(pw + j * 16 * D_MODEL + k0);
                acc[j] = __builtin_amdgcn_mfma_f32_16x16x32_bf16(wf, a0, acc[j], 0, 0, 0);
            }
        }
        // swapped C/D: lane col(c)=m-row, rows q*4+r = p
#pragma unroll
        for (int j = 0; j < 4; j++)
#pragma unroll
            for (int r = 0; r < 4; r++)
                sP[w][j * 16 + q * 4 + r][c] = acc[j][r];
    }
    __syncthreads();

    // phase 2: reduce 4 wave-partials -> bf16 sX[m][p] (swizzled)
    {
        int m = t >> 4, col4 = t & 15;
        float s0 = 0.f, s1 = 0.f, s2 = 0.f, s3 = 0.f;
#pragma unroll
        for (int ww = 0; ww < 4; ww++) {
            s0 += sP[ww][col4 * 4 + 0][m];
            s1 += sP[ww][col4 * 4 + 1][m];
            s2 += sP[ww][col4 * 4 + 2][m];
            s3 += sP[ww][col4 * 4 + 3][m];
        }
        ushort4 o;
        o.x = f2bf(s0); o.y = f2bf(s1); o.z = f2bf(s2); o.w = f2bf(s3);
        int chunk = col4 >> 1, within = (col4 & 1) * 4;
        int swz = chunk ^ (m & 7);
        *reinterpret_cast<ushort4*>(&sX[m * 64 + swz * 8 + within]) = o;
    }
    __syncthreads();

    // phase 3: dt = softplus(xlow @ wdtT^T + b); wave w -> d-range [w*256, +256); write dtb
    {
        bf16x8 af[2];
#pragma unroll
        for (int kk = 0; kk < 2; kk++) {
            int swz = (kk * 4 + q) ^ (c & 7);
            af[kk] = *reinterpret_cast<const bf16x8*>(&sX[c * 64 + swz * 8]);
        }
        int nbase = w * 256;
#pragma unroll 4
        for (int j = 0; j < 16; j++) {
            f32x4 a = {};
#pragma unroll
            for (int kk = 0; kk < 2; kk++) {
                bf16x8 bfr = *reinterpret_cast<const bf16x8*>(
                    &wdtT[(nbase + j * 16 + c) * DT_RANK + kk * 32 + q * 8]);
                a = __builtin_amdgcn_mfma_f32_16x16x32_bf16(bfr, af[kk], a, 0, 0, 0);
            }
            int dcol = nbase + j * 16 + q * 4;
            float4 bv = *reinterpret_cast<const float4*>(&bdt[dcol]);
            ushort4 o;
            {
                float xv = a[0] + bv.x;
                float sp = fmaxf(xv, 0.f) + __logf(1.f + __expf(-fabsf(xv)));
                o.x = f2bf(sp * 0.099f + 0.001f);
            }
            {
                float xv = a[1] + bv.y;
                float sp = fmaxf(xv, 0.f) + __logf(1.f + __expf(-fabsf(xv)));
                o.y = f2bf(sp * 0.099f + 0.001f);
            }
            {
                float xv = a[2] + bv.z;
                float sp = fmaxf(xv, 0.f) + __logf(1.f + __expf(-fabsf(xv)));
                o.z = f2bf(sp * 0.099f + 0.001f);
            }
            {
                float xv = a[3] + bv.w;
                float sp = fmaxf(xv, 0.f) + __logf(1.f + __expf(-fabsf(xv)));
                o.w = f2bf(sp * 0.099f + 0.001f);
            }
            *reinterpret_cast<ushort4*>(&dtb[(m0 + c) * D_MODEL + dcol]) = o;
        }
    }
    __syncthreads();  // drains vmcnt: dtb writes visible to same-CU reads below

    // phase 4: bcw partials for the same 16 rows, K-slice [w*256, +256).
    {
        f32x4 accb[2] = {};
        f32x4 accw = {};
        const unsigned short* pa = xinb + (m0 + c) * D_MODEL + w * 256 + q * 8;
        const unsigned short* pt = dtb + (m0 + c) * D_MODEL + w * 256 + q * 8;
        const unsigned short* pb0 = wxBC + c * D_MODEL + w * 256 + q * 8;
        const unsigned short* pb1 = pb0 + 16 * D_MODEL;
        const unsigned short* pA = anegT + c * D_MODEL + w * 256 + q * 8;
#pragma unroll
        for (int k0 = 0; k0 < 256; k0 += 32) {
            bf16x8 a0 = *reinterpret_cast<const bf16x8*>(pa + k0);
            bf16x8 t0 = *reinterpret_cast<const bf16x8*>(pt + k0);
            bf16x8 b0 = *reinterpret_cast<const bf16x8*>(pb0 + k0);
            bf16x8 b1 = *reinterpret_cast<const bf16x8*>(pb1 + k0);
            bf16x8 bA = *reinterpret_cast<const bf16x8*>(pA + k0);
            bf16x8 g0;
#pragma unroll
            for (int e = 0; e < 8; e++) g0[e] = (__bf16)((float)t0[e] * (float)a0[e]);
            accb[0] = __builtin_amdgcn_mfma_f32_16x16x32_bf16(b0, a0, accb[0], 0, 0, 0);
            accb[1] = __builtin_amdgcn_mfma_f32_16x16x32_bf16(b1, a0, accb[1], 0, 0, 0);
            accw = __builtin_amdgcn_mfma_f32_16x16x32_bf16(bA, g0, accw, 0, 0, 0);
        }
        // swapped C/D: lane col(c) = row, reg rows q*4+r = p (or n)
#pragma unroll
        for (int j = 0; j < 2; j++)
#pragma unroll
            for (int r = 0; r < 4; r++)
                sBC[w][c][j * 16 + q * 4 + r] = accb[j][r];
#pragma unroll
        for (int r = 0; r < 4; r++)
            sBC[w][c][32 + q * 4 + r] = accw[r];
    }
    __syncthreads();

    // phase 5: reduce 4 wave-partials -> FINAL winp = sB*sW, bcC  (256 thr = 16 rows x 16 n)
    {
        int row = t >> 4, n = t & 15;
        float sB = 0.f, sC = 0.f, sW = 0.f;
#pragma unroll
        for (int ww = 0; ww < 4; ww++) {
            sB += sBC[ww][row][n];
            sC += sBC[ww][row][16 + n];
            sW += sBC[ww][row][32 + n];
        }
        winp[(m0 + row) * 16 + n] = sB * sW;
        bcC[(m0 + row) * 16 + n] = sC;
    }
}

// ---------- scan phase 1: chunk-local scan -> h_loc, dtsum (XCD-swizzled; single winp read) ----------
__global__ void __launch_bounds__(256) k_scan1(const unsigned short* __restrict__ dtb,
                                               const float* __restrict__ winp,
                                               const float* __restrict__ aneg,
                                               float* __restrict__ h_loc,
                                               float* __restrict__ dtsum) {
    __shared__ unsigned short s_dt[16][256];
    __shared__ float s_w[16][16];
    int bid0 = blockIdx.x;                      // 512; group dc-siblings per XCD
    int bid = (bid0 & 7) * 64 + (bid0 >> 3);
    int dc = bid & 3;
    int c = (bid >> 2) & (CHUNKS - 1);
    int b = bid >> 8;
    int tid = threadIdx.x;
    int d = dc * 256 + tid;
    float Ad[16];
    const float4* ar = reinterpret_cast<const float4*>(aneg + d * 16);
#pragma unroll
    for (int j = 0; j < 4; j++) {
        float4 a4 = ar[j];
        Ad[4 * j + 0] = a4.x; Ad[4 * j + 1] = a4.y;
        Ad[4 * j + 2] = a4.z; Ad[4 * j + 3] = a4.w;
    }
    float h[16];
#pragma unroll
    for (int n = 0; n < 16; n++) h[n] = 0.f;
    float dts = 0.f;

    int r8 = tid >> 5, col8 = (tid & 31) * 8;
    for (int t0 = 0; t0 < CLEN; t0 += 16) {
        __syncthreads();
        int rowbase = b * SEQ + c * CLEN + t0;
        *reinterpret_cast<uint4*>(&s_dt[r8][col8]) =
            *reinterpret_cast<const uint4*>(dtb + (rowbase + r8) * D_MODEL + dc * 256 + col8);
        *reinterpret_cast<uint4*>(&s_dt[8 + r8][col8]) =
            *reinterpret_cast<const uint4*>(dtb + (rowbase + 8 + r8) * D_MODEL + dc * 256 + col8);
        {
            int r = tid >> 4, n = tid & 15;
            s_w[r][n] = winp[(rowbase + r) * 16 + n];  // coalesced
        }
        __syncthreads();
        for (int r = 0; r < 16; r++) {
            float dtv = bf2f(s_dt[r][tid]);
            dts += dtv;
#pragma unroll
            for (int n = 0; n < 16; n++) {
                float ba = fexp2(dtv * Ad[n]);  // Ad pre-scaled by log2e
                h[n] = fmaf(ba, h[n], s_w[r][n]);
            }
        }
    }
    int base = ((b * CHUNKS + c) * D_MODEL + d) * 16;
#pragma unroll
    for (int j = 0; j < 4; j++) {
        f32x4 v = {h[4 * j], h[4 * j + 1], h[4 * j + 2], h[4 * j + 3]};
        *reinterpret_cast<f32x4*>(h_loc + base + 4 * j) = v;
    }
    dtsum[(b * CHUNKS + c) * D_MODEL + d] = dts;
}

// ---------- scan phase 2: combine chunks, 8-deep prefetch, 256 blocks x 128 thr ----------
__global__ void __launch_bounds__(128) k_scan2(float* __restrict__ h_inout,
                                               const float* __restrict__ dtsum,
                                               const float* __restrict__ aneg) {
    int idx = blockIdx.x * 128 + threadIdx.x;  // 32768
    int n = idx & 15;
    int d = (idx >> 4) & (D_MODEL - 1);
    int b = idx >> 14;
    float A = aneg[d * 16 + n];  // pre-scaled by log2e
    float H = 0.f;
    int off0 = b * CHUNKS * D_MODEL + d;
#pragma unroll 1
    for (int g = 0; g < CHUNKS; g += 8) {
        float hl[8], ds[8];
#pragma unroll
        for (int j = 0; j < 8; j++) {
            int off = off0 + (g + j) * D_MODEL;
            hl[j] = h_inout[off * 16 + n];
            ds[j] = dtsum[off];
        }
#pragma unroll
        for (int j = 0; j < 8; j++) {
            int off = off0 + (g + j) * D_MODEL;
            float P = fexp2(ds[j] * A);
            h_inout[off * 16 + n] = H;
            H = fmaf(P, H, hl[j]);
        }
    }
}

// ---------- scan phase 3: chunk scan from H_in; emit y (XCD-swizzled; single winp/bcC reads) ----------
__global__ void __launch_bounds__(256) k_scan3(const unsigned short* __restrict__ dtb,
                                               const unsigned short* __restrict__ xinb,
                                               const float* __restrict__ winp,
                                               const float* __restrict__ bcC,
                                               const float* __restrict__ aneg,
                                               const float* __restrict__ dp,
                                               const float* __restrict__ H_in,
                                               float* __restrict__ out) {
    __shared__ unsigned short s_dt[16][256], s_u[16][256];
    __shared__ float s_w[16][16], s_c[16][16];
    int bid0 = blockIdx.x;                      // 512; group dc-siblings per XCD
    int bid = (bid0 & 7) * 64 + (bid0 >> 3);
    int dc = bid & 3;
    int c = (bid >> 2) & (CHUNKS - 1);
    int b = bid >> 8;
    int tid = threadIdx.x;
    int d = dc * 256 + tid;
    float Ad[16];
    const float4* ar = reinterpret_cast<const float4*>(aneg + d * 16);
#pragma unroll
    for (int j = 0; j < 4; j++) {
        float4 a4 = ar[j];
        Ad[4 * j + 0] = a4.x; Ad[4 * j + 1] = a4.y;
        Ad[4 * j + 2] = a4.z; Ad[4 * j + 3] = a4.w;
    }
    float Dpd = dp[d];
    float h[16];
    int base = ((b * CHUNKS + c) * D_MODEL + d) * 16;
#pragma unroll
    for (int j = 0; j < 4; j++) {
        f32x4 v = *reinterpret_cast<const f32x4*>(H_in + base + 4 * j);
        h[4 * j] = v[0]; h[4 * j + 1] = v[1]; h[4 * j + 2] = v[2]; h[4 * j + 3] = v[3];
    }

    int r8 = tid >> 5, col8 = (tid & 31) * 8;
    for (int t0 = 0; t0 < CLEN; t0 += 16) {
        __syncthreads();
        int rowbase = b * SEQ + c * CLEN + t0;
        *reinterpret_cast<uint4*>(&s_dt[r8][col8]) =
            *reinterpret_cast<const uint4*>(dtb + (rowbase + r8) * D_MODEL + dc * 256 + col8);
        *reinterpret_cast<uint4*>(&s_dt[8 + r8][col8]) =
            *reinterpret_cast<const uint4*>(dtb + (rowbase + 8 + r8) * D_MODEL + dc * 256 + col8);
        *reinterpret_cast<uint4*>(&s_u[r8][col8]) =
            *reinterpret_cast<const uint4*>(xinb + (rowbase + r8) * D_MODEL + dc * 256 + col8);
        *reinterpret_cast<uint4*>(&s_u[8 + r8][col8]) =
            *reinterpret_cast<const uint4*>(xinb + (rowbase + 8 + r8) * D_MODEL + dc * 256 + col8);
        {
            int r = tid >> 4, n = tid & 15;
            s_w[r][n] = winp[(rowbase + r) * 16 + n];
            s_c[r][n] = bcC[(rowbase + r) * 16 + n];
        }
        __syncthreads();
        for (int r = 0; r < 16; r++) {
            float dtv = bf2f(s_dt[r][tid]), uv = bf2f(s_u[r][tid]);
            float y = Dpd * uv;
#pragma unroll
            for (int n = 0; n < 16; n++) {
                float ba = fexp2(dtv * Ad[n]);  // Ad pre-scaled by log2e
                h[n] = fmaf(ba, h[n], s_w[r][n]);
                y = fmaf(h[n], s_c[r][n], y);
            }
            out[(rowbase + r) * D_MODEL + d] = y;
        }
    }
}

extern "C" void kernel_launch(void* const* d_in, const int* in_sizes, int n_in,
                              void* d_out, int out_size, void* d_ws, size_t ws_size,
                              hipStream_t stream) {
    const float* x     = (const float*)d_in[0];
    const float* w_in  = (const float*)d_in[1];
    const float* w_x   = (const float*)d_in[2];
    const float* w_dt  = (const float*)d_in[3];
    const float* b_dt  = (const float*)d_in[4];
    const float* A_log = (const float*)d_in[5];
    const float* Dp    = (const float*)d_in[6];
    float* out = (float*)d_out;

    char* ws = (char*)d_ws;
    // footprint capped below proven-safe 39124992 B
    // [0, 10485760): scan-phase scratch (h_loc 8 MB + dtsum 512 KB); free during GEMM phase
    unsigned short* bt   = (unsigned short*)(ws + 8388608);    // 2 MB  w_in^T (dead after gemm_xin; dtsum overlays AFTER)
    unsigned short* xinb = (unsigned short*)(ws + 10485760);   // 8 MB
    unsigned short* dtb  = (unsigned short*)(ws + 18874368);   // 8 MB -> ends 27262976
    float* winp          = (float*)(ws + 27262976);            // 256 KB -> 27525120
    float* bcC           = (float*)(ws + 27525120);            // 256 KB -> 27787264
    unsigned short* wxT  = (unsigned short*)(ws + 35651584);   // 128 KB
    unsigned short* wxBC = (unsigned short*)(ws + 35782656);   // 64 KB
    unsigned short* wdtT = (unsigned short*)(ws + 35848192);   // 128 KB
    float* aneg          = (float*)(ws + 35979264);            // 64 KB (pre-scaled by log2e)
    unsigned short* anegT= (unsigned short*)(ws + 36044800);   // 32 KB -> ends 36077568
    // scan-phase overlays (bt dead by then):
    float* h_loc         = (float*)(ws + 0);                   // 8 MB  [b][c][d][n]
    float* dtsum         = (float*)(ws + 8388608);             // 512 KB [b][c][d]

    k_setup<<<1728, 256, 0, stream>>>(w_in, w_x, w_dt, A_log, bt, wxT, wxBC, wdtT, aneg, anegT);
    k_gemm_xin<<<512, 256, 0, stream>>>(x, bt, xinb);
    k_dtbcw<<<256, 256, 0, stream>>>(xinb, wxT, wdtT, b_dt, wxBC, anegT, dtb, winp, bcC);
    k_scan1<<<BATCH * CHUNKS * 4, 256, 0, stream>>>(dtb, winp, aneg, h_loc, dtsum);
    k_scan2<<<256, 128, 0, stream>>>(h_loc, dtsum, aneg);
    k_scan3<<<BATCH * CHUNKS * 4, 256, 0, stream>>>(dtb, xinb, winp, bcC, aneg, Dp, h_loc, out);
}

// Round 12
// 153.154 us; speedup vs baseline: 1.0148x; 1.0148x over previous
//
#include <hip/hip_runtime.h>
#include <hip/hip_bf16.h>

#define D_MODEL 1024
#define D_STATE 16
#define DT_RANK 64
#define SEQ 2048
#define BATCH 2
#define M_TOTAL 4096
#define CHUNKS 64
#define CLEN 32
#define LOG2E 1.44269504088896f

typedef __bf16 bf16x8 __attribute__((ext_vector_type(8)));
typedef float f32x4 __attribute__((ext_vector_type(4)));

__device__ __forceinline__ unsigned short f2bf(float f) {
    union { float f; unsigned int u; } v; v.f = f;
    unsigned int r = v.u + 0x7FFFu + ((v.u >> 16) & 1u);
    return (unsigned short)(r >> 16);
}
__device__ __forceinline__ float bf2f(unsigned short u) {
    union { unsigned int i; float f; } v; v.i = ((unsigned int)u) << 16; return v.f;
}
__device__ __forceinline__ void gload16(const void* g, void* l) {
    __builtin_amdgcn_global_load_lds(
        (const __attribute__((address_space(1))) unsigned int*)g,
        (__attribute__((address_space(3))) unsigned int*)l, 16, 0, 0);
}
__device__ __forceinline__ float fexp2(float x) { return __builtin_amdgcn_exp2f(x); }

// ---------- fused setup ----------
__global__ void __launch_bounds__(256) k_setup(const float* __restrict__ x,
                                               const float* __restrict__ win,
                                               const float* __restrict__ wx,
                                               const float* __restrict__ wdt,
                                               const float* __restrict__ alog,
                                               unsigned short* __restrict__ xb,
                                               unsigned short* __restrict__ bt,
                                               unsigned short* __restrict__ wxT,
                                               unsigned short* __restrict__ wxBC,
                                               unsigned short* __restrict__ wdtT,
                                               float* __restrict__ aneg,
                                               unsigned short* __restrict__ anegT) {
    __shared__ float tile[32][33];
    int blk = blockIdx.x;
    int t = threadIdx.x;
    if (blk < 4096) {  // x -> bf16
        int i = blk * 256 + t;
        float4 v = reinterpret_cast<const float4*>(x)[i];
        ushort4 o;
        o.x = f2bf(v.x); o.y = f2bf(v.y); o.z = f2bf(v.z); o.w = f2bf(v.w);
        reinterpret_cast<ushort4*>(xb)[i] = o;
    } else if (blk < 5120) {  // w_in^T -> bt
        int blk2 = blk - 4096;
        int bx = blk2 & 31, by = blk2 >> 5;
        int tx = t & 31, ty = t >> 5;
        int xc = bx * 32 + tx;
#pragma unroll
        for (int j = 0; j < 4; j++)
            tile[ty + 8 * j][tx] = win[(by * 32 + ty + 8 * j) * D_MODEL + xc];
        __syncthreads();
        int x2 = by * 32 + tx;
#pragma unroll
        for (int j = 0; j < 4; j++)
            bt[(bx * 32 + ty + 8 * j) * D_MODEL + x2] = f2bf(tile[tx][ty + 8 * j]);
    } else if (blk < 5376) {  // wxT[p][e] = w_x[e][p], p<64
        int idx = (blk - 5120) * 256 + t;
        int e = idx & 1023, p = idx >> 10;
        wxT[p * D_MODEL + e] = f2bf(wx[e * 96 + p]);
    } else if (blk < 5504) {  // wxBC[p][e] = w_x[e][64+p], p<32
        int idx = (blk - 5376) * 256 + t;
        int e = idx & 1023, p = idx >> 10;
        wxBC[p * D_MODEL + e] = f2bf(wx[e * 96 + 64 + p]);
    } else if (blk < 5568) {  // aneg (fp32, [d][n], pre-scaled by log2e) + anegT (bf16, [n][d], UNscaled)
        int i = (blk - 5504) * 256 + t;  // 64 blocks -> 16384 exact
        float v = -expf(alog[i]);
        aneg[i] = v * LOG2E;
        anegT[(i & 15) * D_MODEL + (i >> 4)] = f2bf(v);
    } else {  // wdtT[d][k] = w_dt[k][d] bf16  (256 blocks -> 65536)
        int idx = (blk - 5568) * 256 + t;
        int d = idx & 1023, k = idx >> 10;
        wdtT[d * DT_RANK + k] = f2bf(wdt[k * D_MODEL + d]);
    }
}

// ---------- x_in GEMM: x_in = x @ w_in. 64x128 tile, BK=64, dbuf, XOR-swizzle, grid 512 ----------
// XCD-aware bid remap: each XCD gets 8 m-panels x all 8 n-tiles (xb panel fetched once/XCD)
__global__ void __launch_bounds__(256) k_gemm_xin(const unsigned short* __restrict__ xb,
                                                  const unsigned short* __restrict__ bt,
                                                  unsigned short* __restrict__ xinb) {
    __shared__ unsigned short sA[2][64 * 64];
    __shared__ unsigned short sB[2][128 * 64];
    int bid0 = blockIdx.x;               // 512, XCD = bid0 % 8
    int bid = (bid0 & 7) * 64 + (bid0 >> 3);
    int m0 = (bid >> 3) * 64;            // m-major within XCD chunk
    int n0 = (bid & 7) * 128;
    int t = threadIdx.x;
    int lane = t & 63;
    int w = t >> 6;
    int wm = (w >> 1) * 32, wn = (w & 1) * 64;
    int c = lane & 15, q = lane >> 4;

    const unsigned short* gA[2];
    const unsigned short* gB[4];
#pragma unroll
    for (int L = 0; L < 2; L++) {
        int s = L * 256 + t;
        int row = s >> 3, ch = (s & 7) ^ (row & 7);
        gA[L] = xb + (m0 + row) * D_MODEL + ch * 8;
    }
#pragma unroll
    for (int L = 0; L < 4; L++) {
        int s = L * 256 + t;
        int row = s >> 3, ch = (s & 7) ^ (row & 7);
        gB[L] = bt + (n0 + row) * D_MODEL + ch * 8;
    }

    f32x4 acc[2][4] = {};
    {
        char* la = (char*)&sA[0][0] + w * 1024;
        char* lb = (char*)&sB[0][0] + w * 1024;
#pragma unroll
        for (int L = 0; L < 2; L++) gload16(gA[L], la + L * 4096);
#pragma unroll
        for (int L = 0; L < 4; L++) gload16(gB[L], lb + L * 4096);
    }
    int cur = 0;
    for (int it = 0; it < 16; it++) {
        __syncthreads();
        if (it + 1 < 16) {
            int kn = (it + 1) * 64;
            char* la = (char*)&sA[cur ^ 1][0] + w * 1024;
            char* lb = (char*)&sB[cur ^ 1][0] + w * 1024;
#pragma unroll
            for (int L = 0; L < 2; L++) gload16(gA[L] + kn, la + L * 4096);
#pragma unroll
            for (int L = 0; L < 4; L++) gload16(gB[L] + kn, lb + L * 4096);
        }
#pragma unroll
        for (int kk = 0; kk < 2; kk++) {
            int perm = (((kk << 2) | q) ^ (c & 7)) << 3;
            bf16x8 af[2], bfr[4];
#pragma unroll
            for (int i = 0; i < 2; i++)
                af[i] = *reinterpret_cast<const bf16x8*>(&sA[cur][(wm + i * 16 + c) * 64 + perm]);
#pragma unroll
            for (int j = 0; j < 4; j++)
                bfr[j] = *reinterpret_cast<const bf16x8*>(&sB[cur][(wn + j * 16 + c) * 64 + perm]);
            // swapped operands: lane owns 4 consecutive n-cols
#pragma unroll
            for (int i = 0; i < 2; i++)
#pragma unroll
                for (int j = 0; j < 4; j++)
                    acc[i][j] = __builtin_amdgcn_mfma_f32_16x16x32_bf16(bfr[j], af[i], acc[i][j], 0, 0, 0);
        }
        cur ^= 1;
    }
#pragma unroll
    for (int i = 0; i < 2; i++) {
        int row = m0 + wm + i * 16 + c;
#pragma unroll
        for (int j = 0; j < 4; j++) {
            int col = n0 + wn + j * 16 + q * 4;
            ushort4 o;
            o.x = f2bf(acc[i][j][0]); o.y = f2bf(acc[i][j][1]);
            o.z = f2bf(acc[i][j][2]); o.w = f2bf(acc[i][j][3]);
            *reinterpret_cast<ushort4*>(&xinb[row * D_MODEL + col]) = o;
        }
    }
}

// ---------- fused dt+BCW: per-block 16 rows.
// phase 1-3 = proven k_dt2 (xlow wave-ksplit -> LDS reduce -> dt GEMM -> dtb).
// phase 4-5 = bcw for the SAME 16 rows (wave-ksplit K=256, LDS reduce) -> FINAL winp/bcC.
__global__ void __launch_bounds__(256) k_dtbcw(const unsigned short* __restrict__ xinb,
                                               const unsigned short* __restrict__ wxT,
                                               const unsigned short* __restrict__ wdtT,
                                               const float* __restrict__ bdt,
                                               const unsigned short* __restrict__ wxBC,
                                               const unsigned short* __restrict__ anegT,
                                               unsigned short* __restrict__ dtb,
                                               float* __restrict__ winp,
                                               float* __restrict__ bcC) {
    __shared__ float sP[4][64][17];        // xlow wave partials, +1 pad
    __shared__ unsigned short sX[16 * 64]; // bf16 xlow tile, XOR-swizzled
    __shared__ float sBC[4][16][49];       // bcw wave partials: [w][row][p<32 | 32+n], +1 pad
    int m0 = blockIdx.x * 16;              // 256 blocks x 16 rows
    int t = threadIdx.x;
    int lane = t & 63, w = t >> 6;
    int c = lane & 15, q = lane >> 4;

    // phase 1: partial xlow over K slice [w*256, +256)
    {
        f32x4 acc[4] = {};
        const unsigned short* pa = xinb + (m0 + c) * D_MODEL + w * 256 + q * 8;
        const unsigned short* pw = wxT + c * D_MODEL + w * 256 + q * 8;
#pragma unroll
        for (int k0 = 0; k0 < 256; k0 += 32) {
            bf16x8 a0 = *reinterpret_cast<const bf16x8*>(pa + k0);
#pragma unroll
            for (int j = 0; j < 4; j++) {
                bf16x8 wf = *reinterpret_cast<const bf16x8*>(pw + j * 16 * D_MODEL + k0);
                acc[j] = __builtin_amdgcn_mfma_f32_16x16x32_bf16(wf, a0, acc[j], 0, 0, 0);
            }
        }
        // swapped C/D: lane col(c)=m-row, rows q*4+r = p
#pragma unroll
        for (int j = 0; j < 4; j++)
#pragma unroll
            for (int r = 0; r < 4; r++)
                sP[w][j * 16 + q * 4 + r][c] = acc[j][r];
    }
    __syncthreads();

    // phase 2: reduce 4 wave-partials -> bf16 sX[m][p] (swizzled)
    {
        int m = t >> 4, col4 = t & 15;
        float s0 = 0.f, s1 = 0.f, s2 = 0.f, s3 = 0.f;
#pragma unroll
        for (int ww = 0; ww < 4; ww++) {
            s0 += sP[ww][col4 * 4 + 0][m];
            s1 += sP[ww][col4 * 4 + 1][m];
            s2 += sP[ww][col4 * 4 + 2][m];
            s3 += sP[ww][col4 * 4 + 3][m];
        }
        ushort4 o;
        o.x = f2bf(s0); o.y = f2bf(s1); o.z = f2bf(s2); o.w = f2bf(s3);
        int chunk = col4 >> 1, within = (col4 & 1) * 4;
        int swz = chunk ^ (m & 7);
        *reinterpret_cast<ushort4*>(&sX[m * 64 + swz * 8 + within]) = o;
    }
    __syncthreads();

    // phase 3: dt = softplus(xlow @ wdtT^T + b); wave w -> d-range [w*256, +256); write dtb
    {
        bf16x8 af[2];
#pragma unroll
        for (int kk = 0; kk < 2; kk++) {
            int swz = (kk * 4 + q) ^ (c & 7);
            af[kk] = *reinterpret_cast<const bf16x8*>(&sX[c * 64 + swz * 8]);
        }
        int nbase = w * 256;
#pragma unroll 4
        for (int j = 0; j < 16; j++) {
            f32x4 a = {};
#pragma unroll
            for (int kk = 0; kk < 2; kk++) {
                bf16x8 bfr = *reinterpret_cast<const bf16x8*>(
                    &wdtT[(nbase + j * 16 + c) * DT_RANK + kk * 32 + q * 8]);
                a = __builtin_amdgcn_mfma_f32_16x16x32_bf16(bfr, af[kk], a, 0, 0, 0);
            }
            int dcol = nbase + j * 16 + q * 4;
            float4 bv = *reinterpret_cast<const float4*>(&bdt[dcol]);
            ushort4 o;
            {
                float xv = a[0] + bv.x;
                float sp = fmaxf(xv, 0.f) + __logf(1.f + __expf(-fabsf(xv)));
                o.x = f2bf(sp * 0.099f + 0.001f);
            }
            {
                float xv = a[1] + bv.y;
                float sp = fmaxf(xv, 0.f) + __logf(1.f + __expf(-fabsf(xv)));
                o.y = f2bf(sp * 0.099f + 0.001f);
            }
            {
                float xv = a[2] + bv.z;
                float sp = fmaxf(xv, 0.f) + __logf(1.f + __expf(-fabsf(xv)));
                o.z = f2bf(sp * 0.099f + 0.001f);
            }
            {
                float xv = a[3] + bv.w;
                float sp = fmaxf(xv, 0.f) + __logf(1.f + __expf(-fabsf(xv)));
                o.w = f2bf(sp * 0.099f + 0.001f);
            }
            *reinterpret_cast<ushort4*>(&dtb[(m0 + c) * D_MODEL + dcol]) = o;
        }
    }
    __syncthreads();  // drains vmcnt: dtb writes visible to same-CU reads below

    // phase 4: bcw partials for the same 16 rows, K-slice [w*256, +256).
    {
        f32x4 accb[2] = {};
        f32x4 accw = {};
        const unsigned short* pa = xinb + (m0 + c) * D_MODEL + w * 256 + q * 8;
        const unsigned short* pt = dtb + (m0 + c) * D_MODEL + w * 256 + q * 8;
        const unsigned short* pb0 = wxBC + c * D_MODEL + w * 256 + q * 8;
        const unsigned short* pb1 = pb0 + 16 * D_MODEL;
        const unsigned short* pA = anegT + c * D_MODEL + w * 256 + q * 8;
#pragma unroll
        for (int k0 = 0; k0 < 256; k0 += 32) {
            bf16x8 a0 = *reinterpret_cast<const bf16x8*>(pa + k0);
            bf16x8 t0 = *reinterpret_cast<const bf16x8*>(pt + k0);
            bf16x8 b0 = *reinterpret_cast<const bf16x8*>(pb0 + k0);
            bf16x8 b1 = *reinterpret_cast<const bf16x8*>(pb1 + k0);
            bf16x8 bA = *reinterpret_cast<const bf16x8*>(pA + k0);
            bf16x8 g0;
#pragma unroll
            for (int e = 0; e < 8; e++) g0[e] = (__bf16)((float)t0[e] * (float)a0[e]);
            accb[0] = __builtin_amdgcn_mfma_f32_16x16x32_bf16(b0, a0, accb[0], 0, 0, 0);
            accb[1] = __builtin_amdgcn_mfma_f32_16x16x32_bf16(b1, a0, accb[1], 0, 0, 0);
            accw = __builtin_amdgcn_mfma_f32_16x16x32_bf16(bA, g0, accw, 0, 0, 0);
        }
        // swapped C/D: lane col(c) = row, reg rows q*4+r = p (or n)
#pragma unroll
        for (int j = 0; j < 2; j++)
#pragma unroll
            for (int r = 0; r < 4; r++)
                sBC[w][c][j * 16 + q * 4 + r] = accb[j][r];
#pragma unroll
        for (int r = 0; r < 4; r++)
            sBC[w][c][32 + q * 4 + r] = accw[r];
    }
    __syncthreads();

    // phase 5: reduce 4 wave-partials -> FINAL winp = sB*sW, bcC  (256 thr = 16 rows x 16 n)
    {
        int row = t >> 4, n = t & 15;
        float sB = 0.f, sC = 0.f, sW = 0.f;
#pragma unroll
        for (int ww = 0; ww < 4; ww++) {
            sB += sBC[ww][row][n];
            sC += sBC[ww][row][16 + n];
            sW += sBC[ww][row][32 + n];
        }
        winp[(m0 + row) * 16 + n] = sB * sW;
        bcC[(m0 + row) * 16 + n] = sC;
    }
}

// ---------- scan phase 1: chunk-local scan -> h_loc, dtsum (XCD-swizzled; single winp read) ----------
__global__ void __launch_bounds__(256) k_scan1(const unsigned short* __restrict__ dtb,
                                               const float* __restrict__ winp,
                                               const float* __restrict__ aneg,
                                               float* __restrict__ h_loc,
                                               float* __restrict__ dtsum) {
    __shared__ unsigned short s_dt[16][256];
    __shared__ float s_w[16][16];
    int bid0 = blockIdx.x;                      // 512; group dc-siblings per XCD
    int bid = (bid0 & 7) * 64 + (bid0 >> 3);
    int dc = bid & 3;
    int c = (bid >> 2) & (CHUNKS - 1);
    int b = bid >> 8;
    int tid = threadIdx.x;
    int d = dc * 256 + tid;
    float Ad[16];
    const float4* ar = reinterpret_cast<const float4*>(aneg + d * 16);
#pragma unroll
    for (int j = 0; j < 4; j++) {
        float4 a4 = ar[j];
        Ad[4 * j + 0] = a4.x; Ad[4 * j + 1] = a4.y;
        Ad[4 * j + 2] = a4.z; Ad[4 * j + 3] = a4.w;
    }
    float h[16];
#pragma unroll
    for (int n = 0; n < 16; n++) h[n] = 0.f;
    float dts = 0.f;

    int r8 = tid >> 5, col8 = (tid & 31) * 8;
    for (int t0 = 0; t0 < CLEN; t0 += 16) {
        __syncthreads();
        int rowbase = b * SEQ + c * CLEN + t0;
        *reinterpret_cast<uint4*>(&s_dt[r8][col8]) =
            *reinterpret_cast<const uint4*>(dtb + (rowbase + r8) * D_MODEL + dc * 256 + col8);
        *reinterpret_cast<uint4*>(&s_dt[8 + r8][col8]) =
            *reinterpret_cast<const uint4*>(dtb + (rowbase + 8 + r8) * D_MODEL + dc * 256 + col8);
        {
            int r = tid >> 4, n = tid & 15;
            s_w[r][n] = winp[(rowbase + r) * 16 + n];  // coalesced
        }
        __syncthreads();
        for (int r = 0; r < 16; r++) {
            float dtv = bf2f(s_dt[r][tid]);
            dts += dtv;
#pragma unroll
            for (int n = 0; n < 16; n++) {
                float ba = fexp2(dtv * Ad[n]);  // Ad pre-scaled by log2e
                h[n] = fmaf(ba, h[n], s_w[r][n]);
            }
        }
    }
    int base = ((b * CHUNKS + c) * D_MODEL + d) * 16;
#pragma unroll
    for (int j = 0; j < 4; j++) {
        f32x4 v = {h[4 * j], h[4 * j + 1], h[4 * j + 2], h[4 * j + 3]};
        *reinterpret_cast<f32x4*>(h_loc + base + 4 * j) = v;
    }
    dtsum[(b * CHUNKS + c) * D_MODEL + d] = dts;
}

// ---------- scan phase 2: combine chunks, 8-deep prefetch, 256 blocks x 128 thr ----------
__global__ void __launch_bounds__(128) k_scan2(float* __restrict__ h_inout,
                                               const float* __restrict__ dtsum,
                                               const float* __restrict__ aneg) {
    int idx = blockIdx.x * 128 + threadIdx.x;  // 32768
    int n = idx & 15;
    int d = (idx >> 4) & (D_MODEL - 1);
    int b = idx >> 14;
    float A = aneg[d * 16 + n];  // pre-scaled by log2e
    float H = 0.f;
    int off0 = b * CHUNKS * D_MODEL + d;
#pragma unroll 1
    for (int g = 0; g < CHUNKS; g += 8) {
        float hl[8], ds[8];
#pragma unroll
        for (int j = 0; j < 8; j++) {
            int off = off0 + (g + j) * D_MODEL;
            hl[j] = h_inout[off * 16 + n];
            ds[j] = dtsum[off];
        }
#pragma unroll
        for (int j = 0; j < 8; j++) {
            int off = off0 + (g + j) * D_MODEL;
            float P = fexp2(ds[j] * A);
            h_inout[off * 16 + n] = H;
            H = fmaf(P, H, hl[j]);
        }
    }
}

// ---------- scan phase 3: chunk scan from H_in; emit y (XCD-swizzled; single winp/bcC reads) ----------
__global__ void __launch_bounds__(256) k_scan3(const unsigned short* __restrict__ dtb,
                                               const unsigned short* __restrict__ xinb,
                                               const float* __restrict__ winp,
                                               const float* __restrict__ bcC,
                                               const float* __restrict__ aneg,
                                               const float* __restrict__ dp,
                                               const float* __restrict__ H_in,
                                               float* __restrict__ out) {
    __shared__ unsigned short s_dt[16][256], s_u[16][256];
    __shared__ float s_w[16][16], s_c[16][16];
    int bid0 = blockIdx.x;                      // 512; group dc-siblings per XCD
    int bid = (bid0 & 7) * 64 + (bid0 >> 3);
    int dc = bid & 3;
    int c = (bid >> 2) & (CHUNKS - 1);
    int b = bid >> 8;
    int tid = threadIdx.x;
    int d = dc * 256 + tid;
    float Ad[16];
    const float4* ar = reinterpret_cast<const float4*>(aneg + d * 16);
#pragma unroll
    for (int j = 0; j < 4; j++) {
        float4 a4 = ar[j];
        Ad[4 * j + 0] = a4.x; Ad[4 * j + 1] = a4.y;
        Ad[4 * j + 2] = a4.z; Ad[4 * j + 3] = a4.w;
    }
    float Dpd = dp[d];
    float h[16];
    int base = ((b * CHUNKS + c) * D_MODEL + d) * 16;
#pragma unroll
    for (int j = 0; j < 4; j++) {
        f32x4 v = *reinterpret_cast<const f32x4*>(H_in + base + 4 * j);
        h[4 * j] = v[0]; h[4 * j + 1] = v[1]; h[4 * j + 2] = v[2]; h[4 * j + 3] = v[3];
    }

    int r8 = tid >> 5, col8 = (tid & 31) * 8;
    for (int t0 = 0; t0 < CLEN; t0 += 16) {
        __syncthreads();
        int rowbase = b * SEQ + c * CLEN + t0;
        *reinterpret_cast<uint4*>(&s_dt[r8][col8]) =
            *reinterpret_cast<const uint4*>(dtb + (rowbase + r8) * D_MODEL + dc * 256 + col8);
        *reinterpret_cast<uint4*>(&s_dt[8 + r8][col8]) =
            *reinterpret_cast<const uint4*>(dtb + (rowbase + 8 + r8) * D_MODEL + dc * 256 + col8);
        *reinterpret_cast<uint4*>(&s_u[r8][col8]) =
            *reinterpret_cast<const uint4*>(xinb + (rowbase + r8) * D_MODEL + dc * 256 + col8);
        *reinterpret_cast<uint4*>(&s_u[8 + r8][col8]) =
            *reinterpret_cast<const uint4*>(xinb + (rowbase + 8 + r8) * D_MODEL + dc * 256 + col8);
        {
            int r = tid >> 4, n = tid & 15;
            s_w[r][n] = winp[(rowbase + r) * 16 + n];
            s_c[r][n] = bcC[(rowbase + r) * 16 + n];
        }
        __syncthreads();
        for (int r = 0; r < 16; r++) {
            float dtv = bf2f(s_dt[r][tid]), uv = bf2f(s_u[r][tid]);
            float y = Dpd * uv;
#pragma unroll
            for (int n = 0; n < 16; n++) {
                float ba = fexp2(dtv * Ad[n]);  // Ad pre-scaled by log2e
                h[n] = fmaf(ba, h[n], s_w[r][n]);
                y = fmaf(h[n], s_c[r][n], y);
            }
            out[(rowbase + r) * D_MODEL + d] = y;
        }
    }
}

extern "C" void kernel_launch(void* const* d_in, const int* in_sizes, int n_in,
                              void* d_out, int out_size, void* d_ws, size_t ws_size,
                              hipStream_t stream) {
    const float* x     = (const float*)d_in[0];
    const float* w_in  = (const float*)d_in[1];
    const float* w_x   = (const float*)d_in[2];
    const float* w_dt  = (const float*)d_in[3];
    const float* b_dt  = (const float*)d_in[4];
    const float* A_log = (const float*)d_in[5];
    const float* Dp    = (const float*)d_in[6];
    float* out = (float*)d_out;

    char* ws = (char*)d_ws;
    // footprint capped below proven-safe 39124992 B
    unsigned short* xb   = (unsigned short*)(ws + 0);          // 8 MB  (dead after gemm_xin)
    unsigned short* bt   = (unsigned short*)(ws + 8388608);    // 2 MB  w_in^T (dead after gemm_xin)
    unsigned short* xinb = (unsigned short*)(ws + 10485760);   // 8 MB
    unsigned short* dtb  = (unsigned short*)(ws + 18874368);   // 8 MB -> ends 27262976
    float* winp          = (float*)(ws + 27262976);            // 256 KB -> 27525120
    float* bcC           = (float*)(ws + 27525120);            // 256 KB -> 27787264
    unsigned short* wxT  = (unsigned short*)(ws + 35651584);   // 128 KB
    unsigned short* wxBC = (unsigned short*)(ws + 35782656);   // 64 KB
    unsigned short* wdtT = (unsigned short*)(ws + 35848192);   // 128 KB
    float* aneg          = (float*)(ws + 35979264);            // 64 KB (pre-scaled by log2e)
    unsigned short* anegT= (unsigned short*)(ws + 36044800);   // 32 KB -> ends 36077568
    // scan-phase overlays of dead xb/bt regions:
    float* h_loc         = (float*)(ws + 0);                   // 8 MB  [b][c][d][n]
    float* dtsum         = (float*)(ws + 8388608);             // 512 KB [b][c][d]

    k_setup<<<5824, 256, 0, stream>>>(x, w_in, w_x, w_dt, A_log, xb, bt, wxT, wxBC, wdtT, aneg, anegT);
    k_gemm_xin<<<512, 256, 0, stream>>>(xb, bt, xinb);
    k_dtbcw<<<256, 256, 0, stream>>>(xinb, wxT, wdtT, b_dt, wxBC, anegT, dtb, winp, bcC);
    k_scan1<<<BATCH * CHUNKS * 4, 256, 0, stream>>>(dtb, winp, aneg, h_loc, dtsum);
    k_scan2<<<256, 128, 0, stream>>>(h_loc, dtsum, aneg);
    k_scan3<<<BATCH * CHUNKS * 4, 256, 0, stream>>>(dtb, xinb, winp, bcC, aneg, Dp, h_loc, out);
}